// Round 1
// baseline (221.392 us; speedup 1.0000x reference)
//
#include <hip/hip_runtime.h>

// Problem shape from reference setup_inputs(): x = [32, 3, 512, 512] fp32,
// scale_factors = [2] fp32. Output = [32, 3, 512, 512] fp32.
#define BD 32
#define CD 3
#define HD 512
#define WD 512

// Separable diagonal-affine grid_sample, bilinear, zeros padding,
// align_corners=False. One thread -> 4 consecutive w outputs (float4 store).
__global__ __launch_bounds__(256) void stn_kernel(const float* __restrict__ x,
                                                  const float* __restrict__ sf,
                                                  float* __restrict__ out) {
    const float sx = sf[0];
    const float sy = sf[1];

    const int W4 = WD / 4;
    int tid = blockIdx.x * blockDim.x + threadIdx.x;
    const int total = BD * CD * HD * W4;  // 6,291,456 threads
    if (tid >= total) return;

    int w4    = tid % W4;
    int h     = (tid / W4) % HD;
    int plane = tid / (W4 * HD);   // b*C + c

    const float* xp = x + (long long)plane * HD * WD;

    // --- y (row) interpolation params, shared across the 4 outputs ---
    // affine_grid coord: (2h+1)/H - 1 ; scaled ; unnormalized: ((g+1)*H - 1)/2
    float ysn  = (2.0f * (float)h + 1.0f) / (float)HD - 1.0f;
    float gy   = sy * ysn;
    float iy   = ((gy + 1.0f) * (float)HD - 1.0f) * 0.5f;
    float iy0f = floorf(iy);
    float wy1  = iy - iy0f;
    float wy0  = 1.0f - wy1;
    int   iy0  = (int)iy0f;
    int   iy1  = iy0 + 1;
    float fy0  = (iy0 >= 0 && iy0 < HD) ? wy0 : 0.0f;  // weight * validity
    float fy1  = (iy1 >= 0 && iy1 < HD) ? wy1 : 0.0f;
    int   iy0c = min(max(iy0, 0), HD - 1);
    int   iy1c = min(max(iy1, 0), HD - 1);

    const float* row0 = xp + (long long)iy0c * WD;
    const float* row1 = xp + (long long)iy1c * WD;

    float4 res;
    float* resp = (float*)&res;
    int wbase = w4 * 4;

#pragma unroll
    for (int j = 0; j < 4; ++j) {
        int   w    = wbase + j;
        float xsn  = (2.0f * (float)w + 1.0f) / (float)WD - 1.0f;
        float gx   = sx * xsn;
        float ix   = ((gx + 1.0f) * (float)WD - 1.0f) * 0.5f;
        float ix0f = floorf(ix);
        float wx1  = ix - ix0f;
        float wx0  = 1.0f - wx1;
        int   ix0  = (int)ix0f;
        int   ix1  = ix0 + 1;
        float fx0  = (ix0 >= 0 && ix0 < WD) ? wx0 : 0.0f;
        float fx1  = (ix1 >= 0 && ix1 < WD) ? wx1 : 0.0f;
        int   ix0c = min(max(ix0, 0), WD - 1);
        int   ix1c = min(max(ix1, 0), WD - 1);

        float v00 = row0[ix0c];
        float v01 = row0[ix1c];
        float v10 = row1[ix0c];
        float v11 = row1[ix1c];

        // interpolate along H then along W (matches reference order)
        float xh0 = v00 * fy0 + v10 * fy1;
        float xh1 = v01 * fy0 + v11 * fy1;
        resp[j] = xh0 * fx0 + xh1 * fx1;
    }

    float4* outv = (float4*)(out + ((long long)plane * HD + h) * WD + wbase);
    *outv = res;
}

extern "C" void kernel_launch(void* const* d_in, const int* in_sizes, int n_in,
                              void* d_out, int out_size, void* d_ws, size_t ws_size,
                              hipStream_t stream) {
    const float* x  = (const float*)d_in[0];
    const float* sf = (const float*)d_in[1];
    float* out      = (float*)d_out;

    const int total  = BD * CD * HD * (WD / 4);
    const int block  = 256;
    const int grid   = (total + block - 1) / block;
    stn_kernel<<<grid, block, 0, stream>>>(x, sf, out);
}

// Round 2
// 186.783 us; speedup vs baseline: 1.1853x; 1.1853x over previous
//
#include <hip/hip_runtime.h>

// x = [32, 3, 512, 512] fp32, scale_factors = [2] fp32. Output same shape as x.
#define BD 32
#define CD 3
#define HD 512
#define WD 512

// Separable bilinear grid-sample (diagonal affine, zeros padding,
// align_corners=False). One block = one output row (plane, h):
//   1) stage H-interpolated row xh[] into LDS via coalesced float2 loads
//   2) W-gather from LDS (data-dependent indices stay off the L1 pipe)
__global__ __launch_bounds__(256) void stn_kernel(const float* __restrict__ x,
                                                  const float* __restrict__ sf,
                                                  float* __restrict__ out) {
    __shared__ float xh[WD];

    const int plane = blockIdx.x;  // 0..95  (b*C + c)
    const int h     = blockIdx.y;  // 0..511
    const float sx = sf[0];
    const float sy = sf[1];

    // ---- row (H) interpolation params — uniform across the block ----
    float ysn  = (2.0f * (float)h + 1.0f) / (float)HD - 1.0f;
    float iy   = ((sy * ysn + 1.0f) * (float)HD - 1.0f) * 0.5f;
    float iy0f = floorf(iy);
    float wy1  = iy - iy0f;
    int   iy0  = (int)iy0f;
    int   iy1  = iy0 + 1;
    float fy0  = (iy0 >= 0 && iy0 < HD) ? (1.0f - wy1) : 0.0f;
    float fy1  = (iy1 >= 0 && iy1 < HD) ? wy1 : 0.0f;
    int   iy0c = min(max(iy0, 0), HD - 1);
    int   iy1c = min(max(iy1, 0), HD - 1);

    const float* row0 = x + ((long long)plane * HD + iy0c) * WD;
    const float* row1 = x + ((long long)plane * HD + iy1c) * WD;

    const int t = threadIdx.x;  // 0..255, each thread covers 2 w positions

    // ---- stage xh into LDS: coalesced float2 loads, H-interp, LDS store ----
    float2 a = ((const float2*)row0)[t];
    float2 b = ((const float2*)row1)[t];
    float2 c;
    c.x = a.x * fy0 + b.x * fy1;
    c.y = a.y * fy0 + b.y * fy1;
    ((float2*)xh)[t] = c;
    __syncthreads();

    // ---- W interpolation: gather from LDS ----
    float2 o;
#pragma unroll
    for (int j = 0; j < 2; ++j) {
        int   w    = 2 * t + j;
        float xsn  = (2.0f * (float)w + 1.0f) / (float)WD - 1.0f;
        float ix   = ((sx * xsn + 1.0f) * (float)WD - 1.0f) * 0.5f;
        float ix0f = floorf(ix);
        float wx1  = ix - ix0f;
        int   ix0  = (int)ix0f;
        int   ix1  = ix0 + 1;
        float fx0  = (ix0 >= 0 && ix0 < WD) ? (1.0f - wx1) : 0.0f;
        float fx1  = (ix1 >= 0 && ix1 < WD) ? wx1 : 0.0f;
        int   ix0c = min(max(ix0, 0), WD - 1);
        int   ix1c = min(max(ix1, 0), WD - 1);
        ((float*)&o)[j] = xh[ix0c] * fx0 + xh[ix1c] * fx1;
    }

    ((float2*)(out + ((long long)plane * HD + h) * WD))[t] = o;
}

extern "C" void kernel_launch(void* const* d_in, const int* in_sizes, int n_in,
                              void* d_out, int out_size, void* d_ws, size_t ws_size,
                              hipStream_t stream) {
    const float* x  = (const float*)d_in[0];
    const float* sf = (const float*)d_in[1];
    float* out      = (float*)d_out;

    dim3 grid(BD * CD, HD);  // x = plane (96), y = h (512): h, h+1 same XCD
    stn_kernel<<<grid, 256, 0, stream>>>(x, sf, out);
}

// Round 3
// 179.663 us; speedup vs baseline: 1.2323x; 1.0396x over previous
//
#include <hip/hip_runtime.h>

// x = [32, 3, 512, 512] fp32, scale_factors = [2] fp32. Output same shape as x.
#define BD 32
#define CD 3
#define HD 512
#define WD 512
#define TH 8   // output rows per block

// Separable bilinear grid-sample (diagonal affine, zeros padding,
// align_corners=False). One block = TH output rows of one plane:
//  phase A: 8 independent float4 global loads/thread (deep MLP), H-interp,
//           stage xh[TH][WD] in LDS
//  phase B: W-gather from LDS (indices computed once, reused for all TH rows)
__global__ __launch_bounds__(256) void stn_kernel(const float* __restrict__ x,
                                                  const float* __restrict__ sf,
                                                  float* __restrict__ out) {
    __shared__ float xh[TH][WD];  // 16 KB

    const int plane = blockIdx.x;       // 0..95  (b*C + c)
    const int h0    = blockIdx.y * TH;  // 0..511 step TH
    const float sx = sf[0];
    const float sy = sf[1];

    const int t  = threadIdx.x;         // 0..255
    const int rr = t >> 7;              // row-pair parity: 0/1
    const int c4 = (t & 127) << 2;      // float4 column base, covers 512 cols

    const float* xp = x + (long long)plane * HD * WD;

    // ---- phase A: load 4 row-pairs (this thread's rows r = 2*rp + rr) ----
    float4 A[4], B[4];
    float  fy0v[4], fy1v[4];
#pragma unroll
    for (int rp = 0; rp < 4; ++rp) {
        int   h    = h0 + rp * 2 + rr;
        float ysn  = (2.0f * (float)h + 1.0f) / (float)HD - 1.0f;
        float iy   = ((sy * ysn + 1.0f) * (float)HD - 1.0f) * 0.5f;
        float iy0f = floorf(iy);
        float wy1  = iy - iy0f;
        int   iy0  = (int)iy0f;
        int   iy1  = iy0 + 1;
        fy0v[rp]   = (iy0 >= 0 && iy0 < HD) ? (1.0f - wy1) : 0.0f;
        fy1v[rp]   = (iy1 >= 0 && iy1 < HD) ? wy1 : 0.0f;
        int iy0c   = min(max(iy0, 0), HD - 1);
        int iy1c   = min(max(iy1, 0), HD - 1);
        A[rp] = *(const float4*)(xp + (long long)iy0c * WD + c4);
        B[rp] = *(const float4*)(xp + (long long)iy1c * WD + c4);
    }
#pragma unroll
    for (int rp = 0; rp < 4; ++rp) {
        int    r = rp * 2 + rr;
        float4 c;
        c.x = A[rp].x * fy0v[rp] + B[rp].x * fy1v[rp];
        c.y = A[rp].y * fy0v[rp] + B[rp].y * fy1v[rp];
        c.z = A[rp].z * fy0v[rp] + B[rp].z * fy1v[rp];
        c.w = A[rp].w * fy0v[rp] + B[rp].w * fy1v[rp];
        *(float4*)&xh[r][c4] = c;
    }
    __syncthreads();

    // ---- phase B: W interpolation — index math once, gather for all rows ----
    int   ix0c[2], ix1c[2];
    float fx0[2], fx1[2];
#pragma unroll
    for (int j = 0; j < 2; ++j) {
        int   w    = 2 * t + j;
        float xsn  = (2.0f * (float)w + 1.0f) / (float)WD - 1.0f;
        float ix   = ((sx * xsn + 1.0f) * (float)WD - 1.0f) * 0.5f;
        float ix0f = floorf(ix);
        float wx1  = ix - ix0f;
        int   ix0  = (int)ix0f;
        int   ix1  = ix0 + 1;
        fx0[j]     = (ix0 >= 0 && ix0 < WD) ? (1.0f - wx1) : 0.0f;
        fx1[j]     = (ix1 >= 0 && ix1 < WD) ? wx1 : 0.0f;
        ix0c[j]    = min(max(ix0, 0), WD - 1);
        ix1c[j]    = min(max(ix1, 0), WD - 1);
    }

    float* outp = out + ((long long)plane * HD + h0) * WD;
#pragma unroll
    for (int r = 0; r < TH; ++r) {
        float2 o;
        o.x = xh[r][ix0c[0]] * fx0[0] + xh[r][ix1c[0]] * fx1[0];
        o.y = xh[r][ix0c[1]] * fx0[1] + xh[r][ix1c[1]] * fx1[1];
        ((float2*)(outp + (long long)r * WD))[t] = o;
    }
}

extern "C" void kernel_launch(void* const* d_in, const int* in_sizes, int n_in,
                              void* d_out, int out_size, void* d_ws, size_t ws_size,
                              hipStream_t stream) {
    const float* x  = (const float*)d_in[0];
    const float* sf = (const float*)d_in[1];
    float* out      = (float*)d_out;

    dim3 grid(BD * CD, HD / TH);  // 96 x 64 = 6144 blocks
    stn_kernel<<<grid, 256, 0, stream>>>(x, sf, out);
}